// Round 15
// baseline (156.499 us; speedup 1.0000x reference)
//
#include <hip/hip_runtime.h>
#include <hip/hip_bf16.h>

// RUDY routing-demand maps via difference-domain + 2D prefix sum.
// Round-15: DIAGNOSTIC. r8/r13/r14 deposit kernels all floor at 60-124 us
// while every pipe reads idle (VALU 2%, HBM 3%, conflicts 0) and the
// average block runs ~12x over any closed latency model. Three probes with
// identical geometry to the real K2 attribute the cost:
//   probe_empty    = per-block fixed cost (no loop)
//   probe_noatomic = gathers + arithmetic only (asm-sunk, no LDS atomics)
//   probe_nogather = LDS atomics only (synthesized payload, no gathers)
// The real pipeline (r14 structure, unchanged) runs after the probes, so
// output correctness is unaffected. Next round deletes the probes and
// applies the fix the table selects.

#define NBX 256
#define NBY 256
#define NMAP (NBX * NBY)
#define NPAIR 128
#define SL 8               // slices per pair bucket
#define CAP 12288          // max pair bucket ~9k measured (r8); 36% headroom

constexpr float BSX = 2.0f;
constexpr float BSY = 2.0f;
constexpr float INV_H = 1.0f / (4.0f * 50.0f);
constexpr float INV_V = 1.0f / (4.0f * 40.0f);

__device__ __forceinline__ float seg_cum(float t, float mn, float mx) {
    return fminf(fmaxf(t, mn), mx) - mn;
}
__device__ __forceinline__ float second_diff(int i, float bs, float mn, float mx) {
    float u2 = seg_cum((float)(i + 1) * bs, mn, mx);
    float u1 = seg_cum((float)(i) * bs, mn, mx);
    float u0 = seg_cum((float)(i - 1) * bs, mn, mx);
    return (u2 - u1) - (u1 - u0);
}
__device__ __forceinline__ int net_pairs(float4 bb, int* pl) {
    if (bb.y < bb.x) return 0;
    int i0 = (int)floorf(bb.x * 0.5f);
    int i1 = (int)floorf(bb.y * 0.5f);
    int a = i0 >> 1, b = (i0 + 1) >> 1, c = i1 >> 1, d = (i1 + 1) >> 1;
    int n = 0;
    pl[n++] = a;
    if (b != a && b < NPAIR) pl[n++] = b;
    if (c != a && c != b) pl[n++] = c;
    if (d != a && d != b && d != c && d < NPAIR) pl[n++] = d;
    return n;
}

__global__ void zero_ctrl(unsigned* __restrict__ ctrl) {
    ctrl[threadIdx.x] = 0u;
}

// K1: bbox -> 32B record + LDS pair histogram + bucket placement (r14).
__global__ void __launch_bounds__(256) bbox_place(
    const float* __restrict__ pin_pos,
    const int* __restrict__ netpin_start,
    const int* __restrict__ flat_netpin,
    const float* __restrict__ net_weights,
    float4* __restrict__ rec,
    unsigned* __restrict__ gcursor,
    int* __restrict__ bucket,
    int num_nets) {
    __shared__ unsigned cnt[NPAIR], base[NPAIR], loc[NPAIR];
    const int tid = threadIdx.x;
    const int n = blockIdx.x * 256 + tid;
    if (tid < NPAIR) { cnt[tid] = 0u; loc[tid] = 0u; }
    __syncthreads();

    int pl[4];
    int k = 0;
    if (n < num_nets) {
        int s = netpin_start[n], e = netpin_start[n + 1];
        float xmn = 3.0e38f, xmx = -3.0e38f, ymn = 3.0e38f, ymx = -3.0e38f;
        if (e - s == 8 && (s & 3) == 0) {
            int4 a = *reinterpret_cast<const int4*>(flat_netpin + s);
            int4 b = *reinterpret_cast<const int4*>(flat_netpin + s + 4);
            int idx[8] = {a.x, a.y, a.z, a.w, b.x, b.y, b.z, b.w};
#pragma unroll
            for (int p = 0; p < 8; ++p) {
                float2 xy = *reinterpret_cast<const float2*>(pin_pos + 2 * (size_t)idx[p]);
                xmn = fminf(xmn, xy.x);
                xmx = fmaxf(xmx, xy.x);
                ymn = fminf(ymn, xy.y);
                ymx = fmaxf(ymx, xy.y);
            }
        } else {
            for (int p = s; p < e; ++p) {
                int ip = flat_netpin[p];
                float2 xy = *reinterpret_cast<const float2*>(pin_pos + 2 * (size_t)ip);
                xmn = fminf(xmn, xy.x);
                xmx = fmaxf(xmx, xy.x);
                ymn = fminf(ymn, xy.y);
                ymx = fmaxf(ymx, xy.y);
            }
        }
        float4 bb = (e <= s) ? make_float4(3.0e38f, -3.0e38f, 3.0e38f, -3.0e38f)
                             : make_float4(xmn, xmx, ymn, ymx);
        float w = (e > s) ? net_weights[n] : 0.0f;
        rec[2 * (size_t)n]     = bb;
        rec[2 * (size_t)n + 1] = make_float4(w / (bb.w - bb.z),
                                             w / (bb.y - bb.x), 0.f, 0.f);
        k = net_pairs(bb, pl);
    }
    for (int i = 0; i < k; ++i) atomicAdd(&cnt[pl[i]], 1u);
    __syncthreads();
    if (tid < NPAIR && cnt[tid])
        base[tid] = atomicAdd(&gcursor[tid], cnt[tid]);
    __syncthreads();
    for (int i = 0; i < k; ++i) {
        int p = pl[i];
        unsigned slot = base[p] + atomicAdd(&loc[p], 1u);
        if (slot < CAP) bucket[p * CAP + slot] = n;
    }
}

// ---------- PROBE A: per-block fixed cost (no loop) ----------
__global__ void __launch_bounds__(256) probe_empty(
    const unsigned* __restrict__ gcursor,
    float2* __restrict__ Dpart) {
    __shared__ float h0[NBY], v0[NBY], h1[NBY], v1[NBY];
    const int pair  = blockIdx.x & (NPAIR - 1);
    const int slice = blockIdx.x >> 7;
    const int tid = threadIdx.x;
    h0[tid] = 0.f; v0[tid] = 0.f; h1[tid] = 0.f; v1[tid] = 0.f;
    __syncthreads();
    unsigned cu = gcursor[pair];
    asm volatile("" :: "v"(cu));
    size_t sb = (size_t)slice * NMAP;
    Dpart[sb + (size_t)(pair * 2) * NBY + tid]     = make_float2(h0[tid], v0[tid]);
    Dpart[sb + (size_t)(pair * 2 + 1) * NBY + tid] = make_float2(h1[tid], v1[tid]);
}

// ---------- PROBE B: gathers + arithmetic, NO LDS atomics ----------
__global__ void __launch_bounds__(256) probe_noatomic(
    const float4* __restrict__ rec,
    const unsigned* __restrict__ gcursor,
    const int* __restrict__ bucket,
    float2* __restrict__ Dpart) {
    __shared__ float h0[NBY], v0[NBY], h1[NBY], v1[NBY];
    const int pair  = blockIdx.x & (NPAIR - 1);
    const int slice = blockIdx.x >> 7;
    const int tid = threadIdx.x;
    h0[tid] = 0.f; v0[tid] = 0.f; h1[tid] = 0.f; v1[tid] = 0.f;
    __syncthreads();
    const int r0 = pair * 2, r1 = r0 + 1;
    const int boff = pair * CAP;
    unsigned cu = gcursor[pair];
    const int cnt = (int)(cu > CAP ? CAP : cu);
    const int span = (cnt + SL - 1) / SL;
    const int beg = slice * span;
    const int end = min(beg + span, cnt);

    float acc = 0.f;
    auto deposit = [&](int id) {
        float4 bb = rec[2 * (size_t)id];
        float4 wt = rec[2 * (size_t)id + 1];
        float dA = second_diff(r0, BSX, bb.x, bb.y);
        float dB = second_diff(r1, BSX, bb.x, bb.y);
        int j0 = (int)floorf(bb.z * 0.5f);
        int j1 = (int)floorf(bb.w * 0.5f);
        int yi[4];
        yi[0] = j0;
        yi[1] = j0 + 1;
        yi[2] = (j1 > j0 + 1) ? j1 : -1;
        yi[3] = (j1 > j0) ? j1 + 1 : -1;
#pragma unroll
        for (int c2 = 0; c2 < 4; ++c2) {
            int y = yi[c2];
            if (y >= 0 && y < NBY) {
                float dy = second_diff(y, BSY, bb.z, bb.w);
                if (dy != 0.0f) {
                    if (dA != 0.0f) acc += wt.x * dA * dy + wt.y * dA * dy;
                    if (dB != 0.0f) acc += wt.x * dB * dy + wt.y * dB * dy;
                }
            }
        }
    };
    int q = beg + tid;
    for (; q + 768 < end; q += 1024) {
        int a = bucket[boff + q];
        int b = bucket[boff + q + 256];
        int c = bucket[boff + q + 512];
        int d = bucket[boff + q + 768];
        deposit(a); deposit(b); deposit(c); deposit(d);
    }
    for (; q < end; q += 256) deposit(bucket[boff + q]);
    asm volatile("" :: "v"(acc));          // keep the whole chain live
    __syncthreads();
    size_t sb = (size_t)slice * NMAP;
    Dpart[sb + (size_t)r0 * NBY + tid] = make_float2(h0[tid], v0[tid]);
    Dpart[sb + (size_t)r1 * NBY + tid] = make_float2(h1[tid], v1[tid]);
}

// ---------- PROBE C: LDS atomics, NO gathers (synthesized payload) ----------
__global__ void __launch_bounds__(256) probe_nogather(
    const unsigned* __restrict__ gcursor,
    float2* __restrict__ Dpart) {
    __shared__ float h0[NBY], v0[NBY], h1[NBY], v1[NBY];
    const int pair  = blockIdx.x & (NPAIR - 1);
    const int slice = blockIdx.x >> 7;
    const int tid = threadIdx.x;
    h0[tid] = 0.f; v0[tid] = 0.f; h1[tid] = 0.f; v1[tid] = 0.f;
    __syncthreads();
    const int r0 = pair * 2, r1 = r0 + 1;
    unsigned cu = gcursor[pair];
    const int cnt = (int)(cu > CAP ? CAP : cu);
    const int span = (cnt + SL - 1) / SL;
    const int beg = slice * span;
    const int end = min(beg + span, cnt);

    auto fake_deposit = [&](int q) {
        unsigned h = (unsigned)q * 2654435761u;
        float ymn = (float)(h & 1023) * 0.5f;                  // 0..511.5
        float ymx = fminf(ymn + 1.0f + (float)((h >> 10) & 31), 512.0f);
        float xmn = (float)(2 * pair) - 1.5f + (float)((h >> 15) & 3);
        float xmx = xmn + 2.0f + (float)((h >> 17) & 7);
        float4 bb = make_float4(xmn, xmx, ymn, ymx);
        float wtx = 0.001f, wty = 0.0005f;
        float dA = second_diff(r0, BSX, bb.x, bb.y);
        float dB = second_diff(r1, BSX, bb.x, bb.y);
        int j0 = (int)floorf(bb.z * 0.5f);
        int j1 = (int)floorf(bb.w * 0.5f);
        int yi[4];
        yi[0] = j0;
        yi[1] = j0 + 1;
        yi[2] = (j1 > j0 + 1) ? j1 : -1;
        yi[3] = (j1 > j0) ? j1 + 1 : -1;
#pragma unroll
        for (int c2 = 0; c2 < 4; ++c2) {
            int y = yi[c2];
            if (y >= 0 && y < NBY) {
                float dy = second_diff(y, BSY, bb.z, bb.w);
                if (dy != 0.0f) {
                    if (dA != 0.0f) {
                        atomicAdd(&h0[y], wtx * dA * dy);
                        atomicAdd(&v0[y], wty * dA * dy);
                    }
                    if (dB != 0.0f) {
                        atomicAdd(&h1[y], wtx * dB * dy);
                        atomicAdd(&v1[y], wty * dB * dy);
                    }
                }
            }
        }
    };
    int q = beg + tid;
    for (; q + 768 < end; q += 1024) {
        fake_deposit(q); fake_deposit(q + 256);
        fake_deposit(q + 512); fake_deposit(q + 768);
    }
    for (; q < end; q += 256) fake_deposit(q);
    __syncthreads();
    size_t sb = (size_t)slice * NMAP;
    Dpart[sb + (size_t)r0 * NBY + tid] = make_float2(h0[tid], v0[tid]);
    Dpart[sb + (size_t)r1 * NBY + tid] = make_float2(h1[tid], v1[tid]);
}

// K2 (REAL, r14-identical): sliced bucket walk -> LDS deposit -> partials.
__global__ void __launch_bounds__(256) pair_build_sliced(
    const float4* __restrict__ rec,
    const unsigned* __restrict__ gcursor,
    const int* __restrict__ bucket,
    float2* __restrict__ Dpart) {
    __shared__ float h0[NBY], v0[NBY], h1[NBY], v1[NBY];
    const int pair  = blockIdx.x & (NPAIR - 1);
    const int slice = blockIdx.x >> 7;
    const int tid = threadIdx.x;
    h0[tid] = 0.f; v0[tid] = 0.f; h1[tid] = 0.f; v1[tid] = 0.f;
    __syncthreads();
    const int r0 = pair * 2, r1 = r0 + 1;
    const int boff = pair * CAP;
    unsigned cu = gcursor[pair];
    const int cnt = (int)(cu > CAP ? CAP : cu);
    const int span = (cnt + SL - 1) / SL;
    const int beg = slice * span;
    const int end = min(beg + span, cnt);

    auto deposit = [&](int id) {
        float4 bb = rec[2 * (size_t)id];
        float4 wt = rec[2 * (size_t)id + 1];
        float dA = second_diff(r0, BSX, bb.x, bb.y);
        float dB = second_diff(r1, BSX, bb.x, bb.y);
        int j0 = (int)floorf(bb.z * 0.5f);
        int j1 = (int)floorf(bb.w * 0.5f);
        int yi[4];
        yi[0] = j0;
        yi[1] = j0 + 1;
        yi[2] = (j1 > j0 + 1) ? j1 : -1;
        yi[3] = (j1 > j0) ? j1 + 1 : -1;
#pragma unroll
        for (int c2 = 0; c2 < 4; ++c2) {
            int y = yi[c2];
            if (y >= 0 && y < NBY) {
                float dy = second_diff(y, BSY, bb.z, bb.w);
                if (dy != 0.0f) {
                    if (dA != 0.0f) {
                        atomicAdd(&h0[y], wt.x * dA * dy);
                        atomicAdd(&v0[y], wt.y * dA * dy);
                    }
                    if (dB != 0.0f) {
                        atomicAdd(&h1[y], wt.x * dB * dy);
                        atomicAdd(&v1[y], wt.y * dB * dy);
                    }
                }
            }
        }
    };
    int q = beg + tid;
    for (; q + 768 < end; q += 1024) {
        int a = bucket[boff + q];
        int b = bucket[boff + q + 256];
        int c = bucket[boff + q + 512];
        int d = bucket[boff + q + 768];
        deposit(a); deposit(b); deposit(c); deposit(d);
    }
    for (; q < end; q += 256) deposit(bucket[boff + q]);
    __syncthreads();
    size_t sb = (size_t)slice * NMAP;
    Dpart[sb + (size_t)r0 * NBY + tid] = make_float2(h0[tid], v0[tid]);
    Dpart[sb + (size_t)r1 * NBY + tid] = make_float2(h1[tid], v1[tid]);
}

// K3: fold SL slices + inclusive y-scan -> D.
__global__ void __launch_bounds__(256) fold_rows_scan(
    const float2* __restrict__ Dpart,
    float2* __restrict__ D) {
    __shared__ float bh[NBY];
    __shared__ float bv[NBY];
    int r = blockIdx.x, y = threadIdx.x;
    float h = 0.f, v = 0.f;
#pragma unroll
    for (int s = 0; s < SL; ++s) {
        float2 t = Dpart[(size_t)s * NMAP + (size_t)r * NBY + y];
        h += t.x;
        v += t.y;
    }
    bh[y] = h;
    bv[y] = v;
    __syncthreads();
    for (int off = 1; off < NBY; off <<= 1) {
        float ah = (y >= off) ? bh[y - off] : 0.f;
        float av = (y >= off) ? bv[y - off] : 0.f;
        __syncthreads();
        bh[y] += ah;
        bv[y] += av;
        __syncthreads();
    }
    D[(size_t)r * NBY + y] = make_float2(bh[y], bv[y]);
}

// K4: inclusive x-scan per column + finalize.
__global__ void __launch_bounds__(256) scan_cols_finalize(
    const float2* __restrict__ D,
    const float* __restrict__ init_h,
    const float* __restrict__ init_v,
    float* __restrict__ out) {
    __shared__ float bh[NBX];
    __shared__ float bv[NBX];
    int y = blockIdx.x;
    int x = threadIdx.x;
    float2 t = D[x * NBY + y];
    bh[x] = t.x;
    bv[x] = t.y;
    __syncthreads();
    for (int off = 1; off < NBX; off <<= 1) {
        float ah = (x >= off) ? bh[x - off] : 0.f;
        float av = (x >= off) ? bv[x - off] : 0.f;
        __syncthreads();
        bh[x] += ah;
        bv[x] += av;
        __syncthreads();
    }
    int idx = x * NBY + y;
    float H = fmaf(bh[x], INV_H, init_h[idx]);
    float V = fmaf(bv[x], INV_V, init_v[idx]);
    float r = fmaxf(fabsf(H), fabsf(V));
    out[idx]            = r;
    out[idx + NMAP]     = H;
    out[idx + 2 * NMAP] = V;
}

extern "C" void kernel_launch(void* const* d_in, const int* in_sizes, int n_in,
                              void* d_out, int out_size, void* d_ws, size_t ws_size,
                              hipStream_t stream) {
    const float* pin_pos      = (const float*)d_in[0];
    const int*   netpin_start = (const int*)d_in[1];
    const int*   flat_netpin  = (const int*)d_in[2];
    const float* net_weights  = (const float*)d_in[3];
    const float* init_h       = (const float*)d_in[4];
    const float* init_v       = (const float*)d_in[5];
    float* out = (float*)d_out;

    int num_nets = in_sizes[3];
    int Np = (num_nets + 255) & ~255;

    char* w = (char*)d_ws;
    size_t o = 0;
    float4*   rec    = (float4*)(w + o);   o += (size_t)Np * 32;
    int*      bucket = (int*)(w + o);      o += (size_t)NPAIR * CAP * 4;
    float2*   Dpart  = (float2*)(w + o);   o += (size_t)SL * NMAP * 8;
    float2*   D      = (float2*)(w + o);   o += (size_t)NMAP * 8;
    unsigned* ctrl   = (unsigned*)(w + o); o += 512;

    zero_ctrl<<<1, NPAIR, 0, stream>>>(ctrl);
    bbox_place<<<Np / 256, 256, 0, stream>>>(pin_pos, netpin_start, flat_netpin,
                                             net_weights, rec, ctrl, bucket,
                                             num_nets);
    // Diagnostic probes (results overwritten by the real pass below).
    probe_empty<<<NPAIR * SL, 256, 0, stream>>>(ctrl, Dpart);
    probe_noatomic<<<NPAIR * SL, 256, 0, stream>>>(rec, ctrl, bucket, Dpart);
    probe_nogather<<<NPAIR * SL, 256, 0, stream>>>(ctrl, Dpart);
    // Real build.
    pair_build_sliced<<<NPAIR * SL, 256, 0, stream>>>(rec, ctrl, bucket, Dpart);
    fold_rows_scan<<<NBX, 256, 0, stream>>>(Dpart, D);
    scan_cols_finalize<<<NBY, 256, 0, stream>>>(D, init_h, init_v, out);
}

// Round 17
// 97.914 us; speedup vs baseline: 1.5983x; 1.5983x over previous
//
#include <hip/hip_runtime.h>
#include <hip/hip_bf16.h>

// RUDY routing-demand maps via difference-domain + 2D prefix sum.
// Each net deposits wt * u(x) ⊗ v(y); du has <=4 nonzeros (rows i0,i0+1,
// i1,i1+1) -> <=16 difference cells/net; one scan per dim reconstructs maps.
//
// Round-17: r16 (quantized records + 8-deep staging + runtime SL, three
// changes at once) failed the post-timing replay check — unattributable.
// Reverted to r14 exactly (known-good) + ONE change: 8-deep gather staging
// in K2 (ids -> independent record loads -> deposits), the lever r15's
// probes identified (~30us of the 64us build = serial gather latency).
// 32B records, SL=8 compile-time, no quantization.

#define NBX 256
#define NBY 256
#define NMAP (NBX * NBY)
#define NPAIR 128
#define SL 8               // slices per pair bucket
#define CAP 12288          // max pair bucket ~9k measured (r8); 36% headroom

constexpr float BSX = 2.0f;
constexpr float BSY = 2.0f;
constexpr float INV_H = 1.0f / (4.0f * 50.0f);
constexpr float INV_V = 1.0f / (4.0f * 40.0f);

__device__ __forceinline__ float seg_cum(float t, float mn, float mx) {
    return fminf(fmaxf(t, mn), mx) - mn;
}
// First difference of per-bin overlap of [mn,mx]; nonzero only at
// {i0, i0+1, i1, i1+1}.
__device__ __forceinline__ float second_diff(int i, float bs, float mn, float mx) {
    float u2 = seg_cum((float)(i + 1) * bs, mn, mx);
    float u1 = seg_cum((float)(i) * bs, mn, mx);
    float u0 = seg_cum((float)(i - 1) * bs, mn, mx);
    return (u2 - u1) - (u1 - u0);
}
// Row-pair buckets this net touches (deduped, <=4).
__device__ __forceinline__ int net_pairs(float4 bb, int* pl) {
    if (bb.y < bb.x) return 0;                 // degenerate / skipped
    int i0 = (int)floorf(bb.x * 0.5f);
    int i1 = (int)floorf(bb.y * 0.5f);
    int a = i0 >> 1, b = (i0 + 1) >> 1, c = i1 >> 1, d = (i1 + 1) >> 1;
    int n = 0;
    pl[n++] = a;
    if (b != a && b < NPAIR) pl[n++] = b;
    if (c != a && c != b) pl[n++] = c;
    if (d != a && d != b && d != c && d < NPAIR) pl[n++] = d;
    return n;
}

__global__ void zero_ctrl(unsigned* __restrict__ ctrl) {
    ctrl[threadIdx.x] = 0u;   // 128 cursors
}

// K1: per-thread bbox -> 32B record {bbox4, wh, wv}
// + LDS pair histogram + one global cursor reservation per (block,pair).
__global__ void __launch_bounds__(256) bbox_place(
    const float* __restrict__ pin_pos,
    const int* __restrict__ netpin_start,
    const int* __restrict__ flat_netpin,
    const float* __restrict__ net_weights,
    float4* __restrict__ rec,            // [2*Np]: rec[2n]=bbox, rec[2n+1]=wt
    unsigned* __restrict__ gcursor,
    int* __restrict__ bucket,
    int num_nets) {
    __shared__ unsigned cnt[NPAIR], base[NPAIR], loc[NPAIR];
    const int tid = threadIdx.x;
    const int n = blockIdx.x * 256 + tid;
    if (tid < NPAIR) { cnt[tid] = 0u; loc[tid] = 0u; }
    __syncthreads();

    int pl[4];
    int k = 0;
    if (n < num_nets) {
        int s = netpin_start[n], e = netpin_start[n + 1];
        float xmn = 3.0e38f, xmx = -3.0e38f, ymn = 3.0e38f, ymx = -3.0e38f;
        if (e - s == 8 && (s & 3) == 0) {      // common case: 8 pins, aligned
            int4 a = *reinterpret_cast<const int4*>(flat_netpin + s);
            int4 b = *reinterpret_cast<const int4*>(flat_netpin + s + 4);
            int idx[8] = {a.x, a.y, a.z, a.w, b.x, b.y, b.z, b.w};
#pragma unroll
            for (int p = 0; p < 8; ++p) {
                float2 xy = *reinterpret_cast<const float2*>(pin_pos + 2 * (size_t)idx[p]);
                xmn = fminf(xmn, xy.x);
                xmx = fmaxf(xmx, xy.x);
                ymn = fminf(ymn, xy.y);
                ymx = fmaxf(ymx, xy.y);
            }
        } else {
            for (int p = s; p < e; ++p) {
                int ip = flat_netpin[p];
                float2 xy = *reinterpret_cast<const float2*>(pin_pos + 2 * (size_t)ip);
                xmn = fminf(xmn, xy.x);
                xmx = fmaxf(xmx, xy.x);
                ymn = fminf(ymn, xy.y);
                ymx = fmaxf(ymx, xy.y);
            }
        }
        float4 bb = (e <= s) ? make_float4(3.0e38f, -3.0e38f, 3.0e38f, -3.0e38f)
                             : make_float4(xmn, xmx, ymn, ymx);
        float w = (e > s) ? net_weights[n] : 0.0f;
        rec[2 * (size_t)n]     = bb;
        rec[2 * (size_t)n + 1] = make_float4(w / (bb.w - bb.z),   // wh
                                             w / (bb.y - bb.x),   // wv
                                             0.f, 0.f);
        k = net_pairs(bb, pl);
    }
    for (int i = 0; i < k; ++i) atomicAdd(&cnt[pl[i]], 1u);
    __syncthreads();
    if (tid < NPAIR && cnt[tid])
        base[tid] = atomicAdd(&gcursor[tid], cnt[tid]);   // memory-side RMW
    __syncthreads();
    for (int i = 0; i < k; ++i) {
        int p = pl[i];
        unsigned slot = base[p] + atomicAdd(&loc[p], 1u);
        if (slot < CAP) bucket[p * CAP + slot] = n;
    }
}

// K2: block (slice, pair). 8-deep staged walk: 8 ids -> 8 independent 32B
// record loads -> 8 deposits. LDS deposit; partial rows to Dpart[slice].
__global__ void __launch_bounds__(256) pair_build_sliced(
    const float4* __restrict__ rec,
    const unsigned* __restrict__ gcursor,
    const int* __restrict__ bucket,
    float2* __restrict__ Dpart) {        // [SL][NBX][NBY]
    __shared__ float h0[NBY], v0[NBY], h1[NBY], v1[NBY];
    const int pair  = blockIdx.x & (NPAIR - 1);
    const int slice = blockIdx.x >> 7;
    const int tid = threadIdx.x;
    h0[tid] = 0.f; v0[tid] = 0.f; h1[tid] = 0.f; v1[tid] = 0.f;
    __syncthreads();

    const int r0 = pair * 2, r1 = r0 + 1;
    const int boff = pair * CAP;
    unsigned cu = gcursor[pair];
    const int cnt = (int)(cu > CAP ? CAP : cu);
    const int span = (cnt + SL - 1) / SL;
    const int beg = slice * span;
    const int end = min(beg + span, cnt);

    auto deposit = [&](float4 bb, float4 wt) {
        float dA = second_diff(r0, BSX, bb.x, bb.y);
        float dB = second_diff(r1, BSX, bb.x, bb.y);
        int j0 = (int)floorf(bb.z * 0.5f);
        int j1 = (int)floorf(bb.w * 0.5f);
        int yi[4];
        yi[0] = j0;
        yi[1] = j0 + 1;
        yi[2] = (j1 > j0 + 1) ? j1 : -1;       // dedup overlapping candidates
        yi[3] = (j1 > j0) ? j1 + 1 : -1;
#pragma unroll
        for (int c2 = 0; c2 < 4; ++c2) {
            int y = yi[c2];
            if (y >= 0 && y < NBY) {
                float dy = second_diff(y, BSY, bb.z, bb.w);
                if (dy != 0.0f) {
                    if (dA != 0.0f) {
                        atomicAdd(&h0[y], wt.x * dA * dy);
                        atomicAdd(&v0[y], wt.y * dA * dy);
                    }
                    if (dB != 0.0f) {
                        atomicAdd(&h1[y], wt.x * dB * dy);
                        atomicAdd(&v1[y], wt.y * dB * dy);
                    }
                }
            }
        }
    };

    int q = beg + tid;
    // 8-deep staging: ids, then records (independent loads), then deposits.
    for (; q + 7 * 256 < end; q += 8 * 256) {
        int id[8];
#pragma unroll
        for (int j = 0; j < 8; ++j) id[j] = bucket[boff + q + j * 256];
        float4 bb[8], wt[8];
#pragma unroll
        for (int j = 0; j < 8; ++j) {
            bb[j] = rec[2 * (size_t)id[j]];
            wt[j] = rec[2 * (size_t)id[j] + 1];
        }
#pragma unroll
        for (int j = 0; j < 8; ++j) deposit(bb[j], wt[j]);
    }
    for (; q < end; q += 256) {
        int id = bucket[boff + q];
        deposit(rec[2 * (size_t)id], rec[2 * (size_t)id + 1]);
    }
    __syncthreads();

    size_t sb = (size_t)slice * NMAP;
    Dpart[sb + (size_t)r0 * NBY + tid] = make_float2(h0[tid], v0[tid]);
    Dpart[sb + (size_t)r1 * NBY + tid] = make_float2(h1[tid], v1[tid]);
}

// K3: fold SL slices + inclusive y-scan -> D.
__global__ void __launch_bounds__(256) fold_rows_scan(
    const float2* __restrict__ Dpart,
    float2* __restrict__ D) {
    __shared__ float bh[NBY];
    __shared__ float bv[NBY];
    int r = blockIdx.x, y = threadIdx.x;
    float h = 0.f, v = 0.f;
#pragma unroll
    for (int s = 0; s < SL; ++s) {
        float2 t = Dpart[(size_t)s * NMAP + (size_t)r * NBY + y];
        h += t.x;
        v += t.y;
    }
    bh[y] = h;
    bv[y] = v;
    __syncthreads();
    for (int off = 1; off < NBY; off <<= 1) {
        float ah = (y >= off) ? bh[y - off] : 0.f;
        float av = (y >= off) ? bv[y - off] : 0.f;
        __syncthreads();
        bh[y] += ah;
        bv[y] += av;
        __syncthreads();
    }
    D[(size_t)r * NBY + y] = make_float2(bh[y], bv[y]);
}

// K4: inclusive x-scan per column + finalize.
__global__ void __launch_bounds__(256) scan_cols_finalize(
    const float2* __restrict__ D,
    const float* __restrict__ init_h,
    const float* __restrict__ init_v,
    float* __restrict__ out) {
    __shared__ float bh[NBX];
    __shared__ float bv[NBX];
    int y = blockIdx.x;
    int x = threadIdx.x;
    float2 t = D[x * NBY + y];
    bh[x] = t.x;
    bv[x] = t.y;
    __syncthreads();
    for (int off = 1; off < NBX; off <<= 1) {
        float ah = (x >= off) ? bh[x - off] : 0.f;
        float av = (x >= off) ? bv[x - off] : 0.f;
        __syncthreads();
        bh[x] += ah;
        bv[x] += av;
        __syncthreads();
    }
    int idx = x * NBY + y;
    float H = fmaf(bh[x], INV_H, init_h[idx]);
    float V = fmaf(bv[x], INV_V, init_v[idx]);
    float r = fmaxf(fabsf(H), fabsf(V));
    out[idx]            = r;
    out[idx + NMAP]     = H;
    out[idx + 2 * NMAP] = V;
}

extern "C" void kernel_launch(void* const* d_in, const int* in_sizes, int n_in,
                              void* d_out, int out_size, void* d_ws, size_t ws_size,
                              hipStream_t stream) {
    const float* pin_pos      = (const float*)d_in[0];
    const int*   netpin_start = (const int*)d_in[1];
    const int*   flat_netpin  = (const int*)d_in[2];
    const float* net_weights  = (const float*)d_in[3];
    const float* init_h       = (const float*)d_in[4];
    const float* init_v       = (const float*)d_in[5];
    float* out = (float*)d_out;

    int num_nets = in_sizes[3];
    int Np = (num_nets + 255) & ~255;

    // ws layout (~14.0 MB @100k nets; r12/r14 proved >=14.25 MB available):
    // [rec 2*Np*16][bucket 128*CAP*4][Dpart SL*NMAP*8][D NMAP*8][ctrl 512]
    char* w = (char*)d_ws;
    size_t o = 0;
    float4*   rec    = (float4*)(w + o);   o += (size_t)Np * 32;
    int*      bucket = (int*)(w + o);      o += (size_t)NPAIR * CAP * 4;
    float2*   Dpart  = (float2*)(w + o);   o += (size_t)SL * NMAP * 8;
    float2*   D      = (float2*)(w + o);   o += (size_t)NMAP * 8;
    unsigned* ctrl   = (unsigned*)(w + o); o += 512;

    zero_ctrl<<<1, NPAIR, 0, stream>>>(ctrl);
    bbox_place<<<Np / 256, 256, 0, stream>>>(pin_pos, netpin_start, flat_netpin,
                                             net_weights, rec, ctrl, bucket,
                                             num_nets);
    pair_build_sliced<<<NPAIR * SL, 256, 0, stream>>>(rec, ctrl, bucket, Dpart);
    fold_rows_scan<<<NBX, 256, 0, stream>>>(Dpart, D);
    scan_cols_finalize<<<NBY, 256, 0, stream>>>(D, init_h, init_v, out);
}